// Round 3
// baseline (745.446 us; speedup 1.0000x reference)
//
#include <hip/hip_runtime.h>

// DenseEquivariantIrrep: B=32768, C=32, F=32, NS=48, irreps: 4x(d=1), 2x(d=2), 4x(d=3)
// y[b,f,s] = sum_j (sum_{c,r} (x[b,c,:]@fwd)[n,p,r] * (kernel[f,c,:]@fwd)[n,r,q]) * inv[j,s] + bias[f]
//
// R5 = R2 + ONE change: kh staged into LDS via global_load_lds (double-buffered
// slice-PAIRS, 2 pairs ahead, 1 barrier / 2 c-iters). R4's failure was a
// staging/read layout mismatch: pairs land LINEARLY (slice s+1 at +416 f4, no
// pad possible with global_load_lds) but reads used +448. Fixed to +416.
// Stage A reverted to R2's reg-staged PADDED layout (QB4=417, QC4=13): R4's
// linear rows (QC4=12) made stage B 8-way bank-conflicted within 16-lane
// groups (4c mod 8 in {0,4}) -- unforced regression.
// Accumulation order identical to R2 -> bit-identical output (absmax 0.125).
// LDS 53,376 + 26,624 = 80,000 B -> 2 blocks/CU (8 waves/CU).

#define QB4 417   // float4 stride per b-row in LDS (b + 5c) mod 8 spreads bank quads
#define QC4 13    // float4 stride per c-row

typedef __attribute__((address_space(3))) void lds_void;
typedef const __attribute__((address_space(1))) void glob_void;

__device__ __forceinline__ void gload16(const void* g, void* l) {
    // wave-level: LDS dest = wave-uniform base + lane*16; global src is per-lane.
    __builtin_amdgcn_global_load_lds((glob_void*)g, (lds_void*)l, 16, 0, 0);
}

// ---- prep 1: fwdT[j][t] = fwd[t][j];  invT[s][j] = fwd[s][j] * d_j/48 ----
__global__ void prep_ft(const float* __restrict__ d1, const float* __restrict__ d2,
                        const float* __restrict__ d3,
                        float* __restrict__ fwdT, float* __restrict__ invT) {
    int id = blockIdx.x * 256 + threadIdx.x;   // 0..2303
    if (id >= 48 * 48) return;
    int j = id / 48, t = id - j * 48;
    float v, scale;
    if (j < 4) {                       // d=1 irreps: [4][48][1][1]
        v = d1[j * 48 + t];
        scale = 1.0f / 48.0f;
    } else if (j < 12) {               // d=2 irreps: [2][48][2][2]
        int r = j - 4;
        int i = r >> 2, pq = r & 3;
        v = d2[i * 192 + t * 4 + pq];
        scale = 2.0f / 48.0f;
    } else {                           // d=3 irreps: [4][48][3][3]
        int r = j - 12;
        int i = r / 9, pq = r - i * 9;
        v = d3[i * 432 + t * 9 + pq];
        scale = 3.0f / 48.0f;
    }
    fwdT[j * 48 + t] = v;
    invT[t * 48 + j] = v * scale;      // transposed so stage D rows are contiguous
}

// ---- prep 2: gkh[c][f][52]: gkh[(c*32+f)*52 + j] = sum_t kernel[f][c][t]*fwdT[j][t] ----
// c-major slices (slice = 32 f x 13 f4 = 416 f4) for LDS pair staging; j=48..51 pad unused.
__global__ void prep_kh(const float* __restrict__ kern, const float* __restrict__ fwdT,
                        float* __restrict__ gkh) {
    int id = blockIdx.x * 256 + threadIdx.x;   // 0..4095
    int f = id >> 7;
    int c = (id >> 2) & 31;
    int jq = id & 3;
    float kr[48];
    const float4* kp = (const float4*)(kern + (f * 32 + c) * 48);
    #pragma unroll
    for (int k = 0; k < 12; ++k) {
        float4 v = kp[k];
        kr[4*k] = v.x; kr[4*k+1] = v.y; kr[4*k+2] = v.z; kr[4*k+3] = v.w;
    }
    for (int jj = 0; jj < 12; ++jj) {
        int j = jq * 12 + jj;
        const float* fr = fwdT + j * 48;
        float acc = 0.0f;
        #pragma unroll
        for (int t = 0; t < 48; ++t) acc = fmaf(kr[t], fr[t], acc);
        gkh[(c * 32 + f) * 52 + j] = acc;
    }
}

// stage kh slices s, s+1 (s even) into LDS pair (s>>1)&1: exactly 13 chunks of 1KB
// (pair = 832 f4 = 13*64). Lands LINEARLY: slice s at +0, slice s+1 at +416 f4.
#define STAGE_KH2(s) do { \
    const float4* _src = gk + (s) * 416 + lane; \
    float4* _dst = &khlds[(((s) >> 1) & 1) * 832]; \
    _Pragma("unroll") \
    for (int ch = 0; ch < 13; ++ch) \
        if ((ch & 3) == wv) gload16(_src + ch * 64, _dst + ch * 64); \
} while (0)

// ---- fused main: block = 8 b-rows x 32 f ----
__global__ __launch_bounds__(256) __attribute__((amdgpu_waves_per_eu(2, 2)))
void fused_main(
    const float* __restrict__ x,
    const float* __restrict__ fwdT,
    const float* __restrict__ invT,
    const float* __restrict__ gkh,
    const float* __restrict__ bias,
    float* __restrict__ out) {
    __shared__ float4 xlds[8 * QB4];    // 53,376 B: x/xh tile [8][32][13f4 padded]
    __shared__ float4 khlds[2 * 832];   // 26,624 B: 2 pairs x 2 slices x 416 f4
    const int tid = threadIdx.x;
    const int wv = tid >> 6;
    const int lane = tid & 63;
    const long long b0 = (long long)blockIdx.x * 8;
    const float4* gk = (const float4*)gkh;   // slice stride 416 f4

    // ---- Stage A: coalesced load of x tile [8][32][48] into LDS (padded) ----
    const float4* xg = (const float4*)x + b0 * 384;   // 384 float4 per b-row
    #pragma unroll
    for (int it = 0; it < 12; ++it) {
        int v = tid + it * 256;          // 0..3071
        int b = v / 384;
        int w = v - b * 384;             // float4 idx within row
        int c = w / 12;
        int t4 = w - c * 12;
        xlds[b * QB4 + c * QC4 + t4] = xg[v];
    }
    // prologue kh staging: slices 0..3 into both pairs (drained by first barrier)
    STAGE_KH2(0);
    STAGE_KH2(2);
    __syncthreads();

    // ---- Stage B: xh[b][c][:] = x[b][c][:] @ fwd  (in-place, thread = (b,c)) ----
    {
        const int b = tid >> 5, c = tid & 31;
        float4* row = &xlds[b * QB4 + c * QC4];
        float xr[48];
        #pragma unroll
        for (int k = 0; k < 12; ++k) {
            float4 v = row[k];
            xr[4*k] = v.x; xr[4*k+1] = v.y; xr[4*k+2] = v.z; xr[4*k+3] = v.w;
        }
        for (int jc = 0; jc < 12; ++jc) {      // rolled: live = xr[48] + h[4]
            float h[4];
            #pragma unroll
            for (int u = 0; u < 4; ++u) {
                const float* fr = fwdT + (jc * 4 + u) * 48;   // uniform -> s_load
                float acc = 0.0f;
                #pragma unroll
                for (int t = 0; t < 48; ++t) acc = fmaf(xr[t], fr[t], acc);
                h[u] = acc;
            }
            row[jc] = make_float4(h[0], h[1], h[2], h[3]);
        }
    }
    __syncthreads();

    // ---- Stage C: yh[j] = sum_{c,r} xh * kh   (thread = (b,f)) ----
    // kh read from LDS pair double-buffer, staged 2 pairs ahead; 1 barrier / 2 c-iters.
    {
        const int b = tid & 7, f = tid >> 3;
        float yh[48];
        #pragma unroll
        for (int j = 0; j < 48; ++j) yh[j] = 0.0f;

        const float4* xrow0 = &xlds[b * QB4];

        for (int c = 0; c < 32; c += 2) {
            #pragma unroll
            for (int u = 0; u < 2; ++u) {
                const int cc = c + u;
                const float4* xrow = xrow0 + cc * QC4;
                // pair base + slice-within-pair (LINEAR: +416 f4) + f row (13 f4)
                const float4* kp = &khlds[((cc >> 1) & 1) * 832 + (cc & 1) * 416 + f * 13];

                // -- half 1: d1 + d2 irreps (floats 0..11) --
                {
                    float xr[12], kr[12];
                    #pragma unroll
                    for (int k = 0; k < 3; ++k) {
                        float4 v = xrow[k];
                        xr[4*k] = v.x; xr[4*k+1] = v.y; xr[4*k+2] = v.z; xr[4*k+3] = v.w;
                        float4 w = kp[k];
                        kr[4*k] = w.x; kr[4*k+1] = w.y; kr[4*k+2] = w.z; kr[4*k+3] = w.w;
                    }
                    #pragma unroll
                    for (int n = 0; n < 4; ++n) yh[n] = fmaf(xr[n], kr[n], yh[n]);
                    #pragma unroll
                    for (int n = 0; n < 2; ++n) {
                        const int o = 4 + 4 * n;
                        #pragma unroll
                        for (int p = 0; p < 2; ++p) {
                            #pragma unroll
                            for (int q = 0; q < 2; ++q) {
                                float s = yh[o + 2*p + q];
                                s = fmaf(xr[o + 2*p + 0], kr[o + 0 + q], s);
                                s = fmaf(xr[o + 2*p + 1], kr[o + 2 + q], s);
                                yh[o + 2*p + q] = s;
                            }
                        }
                    }
                }
                // -- half 2: d3 irreps (floats 12..47) --
                {
                    float xr[36], kr[36];
                    #pragma unroll
                    for (int k = 0; k < 9; ++k) {
                        float4 v = xrow[3 + k];
                        xr[4*k] = v.x; xr[4*k+1] = v.y; xr[4*k+2] = v.z; xr[4*k+3] = v.w;
                        float4 w = kp[3 + k];
                        kr[4*k] = w.x; kr[4*k+1] = w.y; kr[4*k+2] = w.z; kr[4*k+3] = w.w;
                    }
                    #pragma unroll
                    for (int n = 0; n < 4; ++n) {
                        const int o = 9 * n;
                        #pragma unroll
                        for (int p = 0; p < 3; ++p) {
                            #pragma unroll
                            for (int q = 0; q < 3; ++q) {
                                float s = yh[12 + o + 3*p + q];
                                s = fmaf(xr[o + 3*p + 0], kr[o + 0 + q], s);
                                s = fmaf(xr[o + 3*p + 1], kr[o + 3 + q], s);
                                s = fmaf(xr[o + 3*p + 2], kr[o + 6 + q], s);
                                yh[12 + o + 3*p + q] = s;
                            }
                        }
                    }
                }
            }
            // all waves done reading pair (c>>1)&1; refill it for c+4. Its loads
            // are drained by the NEXT iteration's barrier (full compute between).
            if (c < 30) __syncthreads();
            if (c < 28) STAGE_KH2(c + 4);
        }

        // ---- Stage D: y[s] = sum_j yh[j] * invT[s][j] + bias[f] ----
        // loop-interchanged: 4 outputs at a time, live = yh[48] + a[4]
        const float bf = bias[f];
        float4* op = (float4*)(out + ((b0 + (long long)b) * 32 + f) * 48);
        for (int sc = 0; sc < 12; ++sc) {
            float a[4];
            #pragma unroll
            for (int u = 0; u < 4; ++u) {
                const float* ir = invT + (sc * 4 + u) * 48;   // uniform -> s_load
                float acc = bf;
                #pragma unroll
                for (int j = 0; j < 48; ++j) acc = fmaf(yh[j], ir[j], acc);
                a[u] = acc;
            }
            op[sc] = make_float4(a[0], a[1], a[2], a[3]);
        }
    }
}

extern "C" void kernel_launch(void* const* d_in, const int* in_sizes, int n_in,
                              void* d_out, int out_size, void* d_ws, size_t ws_size,
                              hipStream_t stream) {
    const float* x    = (const float*)d_in[0];
    const float* kern = (const float*)d_in[1];
    const float* bias = (const float*)d_in[2];
    const float* d1   = (const float*)d_in[3];
    const float* d2   = (const float*)d_in[4];
    const float* d3   = (const float*)d_in[5];
    float* out = (float*)d_out;

    float* fwdT = (float*)d_ws;          // 2,304 floats
    float* invT = fwdT + 2304;           // 2,304 floats
    float* gkh  = invT + 2304;           // 32*32*52 = 53,248 floats

    prep_ft<<<9, 256, 0, stream>>>(d1, d2, d3, fwdT, invT);
    prep_kh<<<16, 256, 0, stream>>>(kern, fwdT, gkh);
    fused_main<<<32768 / 8, 256, 0, stream>>>(x, fwdT, invT, gkh, bias, out);
}